// Round 1
// baseline (45.038 us; speedup 1.0000x reference)
//
#include <hip/hip_runtime.h>

#define NROWS 1048576
#define NCLS 27
#define RPB 256                 // rows per block == threads per block
#define NBLK (NROWS / RPB)      // 4096

__global__ __launch_bounds__(256) void l1pen_partial(
    const float* __restrict__ pred, const float* __restrict__ tgt,
    const float* __restrict__ pen, float* __restrict__ partial) {
  __shared__ float sp[RPB * NCLS];          // 27648 B
  __shared__ float st[RPB * NCLS];          // 27648 B
  __shared__ float spen[NCLS * NCLS];       // 2916 B
  __shared__ float sred[4];
  const int tid = threadIdx.x;

  // penalty LUT -> LDS (L2-resident after first blocks)
  for (int i = tid; i < NCLS * NCLS; i += 256) spen[i] = pen[i];

  // coalesced float4 staging of 256 rows of pred/tgt
  const size_t base = (size_t)blockIdx.x * (RPB * NCLS);
  const float4* p4 = (const float4*)(pred + base);
  const float4* t4 = (const float4*)(tgt + base);
  float4* sp4 = (float4*)sp;
  float4* st4 = (float4*)st;
  constexpr int NV4 = RPB * NCLS / 4;       // 1728
  #pragma unroll
  for (int i = 0; i < NV4 / 256; ++i) {     // 6 full rounds
    sp4[tid + i * 256] = p4[tid + i * 256];
    st4[tid + i * 256] = t4[tid + i * 256];
  }
  {
    const int i = tid + (NV4 / 256) * 256;  // remainder: 192 vec4
    if (i < NV4) { sp4[i] = p4[i]; st4[i] = t4[i]; }
  }
  __syncthreads();

  // per-thread row: L1 sum + first-occurrence argmax of pred and tgt.
  // LDS stride 27 words between lanes -> gcd(27,32)=1 -> conflict-free.
  const float* rp = sp + tid * NCLS;
  const float* rt = st + tid * NCLS;
  float p0 = rp[0], t0 = rt[0];
  float l1 = fabsf(p0 - t0);
  float pbest = p0, tbest = t0;
  int pc = 0, lc = 0;
  #pragma unroll
  for (int c = 1; c < NCLS; ++c) {
    float p = rp[c], t = rt[c];
    l1 += fabsf(p - t);
    if (p > pbest) { pbest = p; pc = c; }
    if (t > tbest) { tbest = t; lc = c; }
  }
  float val = l1 * spen[pc * NCLS + lc];

  // wave64 tree reduce, then cross-wave via LDS
  #pragma unroll
  for (int off = 32; off; off >>= 1) val += __shfl_down(val, off);
  if ((tid & 63) == 0) sred[tid >> 6] = val;
  __syncthreads();
  if (tid == 0)
    partial[blockIdx.x] = (sred[0] + sred[1]) + (sred[2] + sred[3]);
}

__global__ __launch_bounds__(256) void l1pen_final(
    const float* __restrict__ partial, float* __restrict__ out) {
  __shared__ double sred[4];
  double s = 0.0;
  for (int i = threadIdx.x; i < NBLK; i += 256) s += (double)partial[i];
  #pragma unroll
  for (int off = 32; off; off >>= 1) s += __shfl_down(s, off);
  if ((threadIdx.x & 63) == 0) sred[threadIdx.x >> 6] = s;
  __syncthreads();
  if (threadIdx.x == 0)
    out[0] = (float)(((sred[0] + sred[1]) + (sred[2] + sred[3])) / (double)NROWS);
}

extern "C" void kernel_launch(void* const* d_in, const int* in_sizes, int n_in,
                              void* d_out, int out_size, void* d_ws, size_t ws_size,
                              hipStream_t stream) {
  const float* pred = (const float*)d_in[0];
  const float* tgt  = (const float*)d_in[1];
  const float* pen  = (const float*)d_in[2];
  float* out        = (float*)d_out;
  float* partial    = (float*)d_ws;   // 4096 floats = 16 KB scratch

  l1pen_partial<<<NBLK, 256, 0, stream>>>(pred, tgt, pen, partial);
  l1pen_final<<<1, 256, 0, stream>>>(partial, out);
}